// Round 1
// baseline (544.536 us; speedup 1.0000x reference)
//
#include <hip/hip_runtime.h>
#include <math.h>

constexpr int NN  = 50000;   // nodes
constexpr int NE  = 800000;  // edges
constexpr int IND = 128;     // input dim
constexpr int HCD = 128;     // heads*channels
constexpr float NEG_SLOPE = 0.2f;

// ---------------------------------------------------------------------------
// K1: dual GEMM  xl = x@Wl + bl ; xr = x@Wr + br   (fp32, register-tiled)
// block tile: 64 nodes x 256 cols (cols 0..127 -> Wl, 128..255 -> Wr)
// 256 threads, 8x8 per thread, K staged in chunks of 32.
// ---------------------------------------------------------------------------
constexpr int GN = 64, GC = 256, GK = 32;
constexpr int XSP = GN + 4;   // pad so transposed-stage writes are conflict-free

__global__ __launch_bounds__(256) void gemm_xlr(
    const float* __restrict__ x, const float* __restrict__ Wl, const float* __restrict__ Wr,
    const float* __restrict__ bl, const float* __restrict__ br,
    float* __restrict__ xl, float* __restrict__ xr)
{
    __shared__ float xs[GK][XSP];   // x tile transposed: xs[k][n]
    __shared__ float ws[GK][GC];    // W tile: ws[k][c]
    const int tid = threadIdx.x;
    const int bn  = blockIdx.x * GN;
    const int tn  = (tid >> 5) * 8;   // node offset 0..56
    const int tc  = (tid & 31) * 8;   // col offset 0..248

    float acc[8][8];
#pragma unroll
    for (int a = 0; a < 8; ++a)
#pragma unroll
        for (int b = 0; b < 8; ++b) acc[a][b] = 0.f;

    for (int k0 = 0; k0 < IND; k0 += GK) {
        // stage x transposed: thread i -> n = i>>5, k = i&31 (coalesced global,
        // LDS write addr = k*XSP + n, XSP=68 -> stride 17 banks: conflict-free)
        for (int i = tid; i < GN * GK; i += 256) {
            int n = i >> 5, k = i & 31;
            int node = bn + n;
            xs[k][n] = (node < NN) ? x[node * IND + k0 + k] : 0.f;
        }
        // stage W rows (coalesced)
        for (int k = 0; k < GK; ++k) {
            float v = (tid < HCD) ? Wl[(k0 + k) * HCD + tid]
                                  : Wr[(k0 + k) * HCD + (tid - HCD)];
            ws[k][tid] = v;
        }
        __syncthreads();
#pragma unroll 4
        for (int k = 0; k < GK; ++k) {
            float4 x0 = *reinterpret_cast<const float4*>(&xs[k][tn]);
            float4 x1 = *reinterpret_cast<const float4*>(&xs[k][tn + 4]);
            float4 w0 = *reinterpret_cast<const float4*>(&ws[k][tc]);
            float4 w1 = *reinterpret_cast<const float4*>(&ws[k][tc + 4]);
            float xv[8] = {x0.x, x0.y, x0.z, x0.w, x1.x, x1.y, x1.z, x1.w};
            float wv[8] = {w0.x, w0.y, w0.z, w0.w, w1.x, w1.y, w1.z, w1.w};
#pragma unroll
            for (int a = 0; a < 8; ++a)
#pragma unroll
                for (int b = 0; b < 8; ++b) acc[a][b] += xv[a] * wv[b];
        }
        __syncthreads();
    }
#pragma unroll
    for (int a = 0; a < 8; ++a) {
        int node = bn + tn + a;
        if (node >= NN) continue;
#pragma unroll
        for (int b = 0; b < 8; ++b) {
            int c = tc + b;
            float v = acc[a][b];
            if (c < HCD) xl[node * HCD + c] = v + bl[c];
            else         xr[node * HCD + (c - HCD)] = v + br[c - HCD];
        }
    }
}

// ---------------------------------------------------------------------------
// K2: in-degree count
// ---------------------------------------------------------------------------
__global__ __launch_bounds__(256) void deg_kernel(const int* __restrict__ dst,
                                                  int* __restrict__ deg)
{
    int e = blockIdx.x * 256 + threadIdx.x;
    if (e < NE) atomicAdd(&deg[dst[e]], 1);
}

// ---------------------------------------------------------------------------
// K3: exclusive scan of deg -> off (single block, 1024 threads)
// ---------------------------------------------------------------------------
__global__ __launch_bounds__(1024) void scan_kernel(const int* __restrict__ deg,
                                                    int* __restrict__ off)
{
    __shared__ int tsum[1024];
    const int tid = threadIdx.x;
    const int per = (NN + 1023) / 1024;   // 49
    const int base = tid * per;
    int s = 0;
    for (int i = 0; i < per; ++i) {
        int idx = base + i;
        if (idx < NN) s += deg[idx];
    }
    tsum[tid] = s;
    __syncthreads();
    for (int d = 1; d < 1024; d <<= 1) {
        int v = (tid >= d) ? tsum[tid - d] : 0;
        __syncthreads();
        tsum[tid] += v;
        __syncthreads();
    }
    int run = tsum[tid] - s;   // exclusive prefix of this thread's chunk
    for (int i = 0; i < per; ++i) {
        int idx = base + i;
        if (idx < NN) { off[idx] = run; run += deg[idx]; }
    }
    if (tid == 1023) off[NN] = run;   // = NE
}

// ---------------------------------------------------------------------------
// K4: CSR fill — store src node id and edge_attr value per CSR slot
// ---------------------------------------------------------------------------
__global__ __launch_bounds__(256) void fill_kernel(
    const int* __restrict__ src, const int* __restrict__ dst,
    const float* __restrict__ ea, const int* __restrict__ off,
    int* __restrict__ cursor, int* __restrict__ csr_src, float* __restrict__ csr_ea)
{
    int e = blockIdx.x * 256 + threadIdx.x;
    if (e >= NE) return;
    int d = dst[e];
    int pos = atomicAdd(&cursor[d], 1);
    int idx = off[d] + pos;
    csr_src[idx] = src[e];
    csr_ea[idx]  = ea[e];
}

// ---------------------------------------------------------------------------
// K5: per-node fused attention + online softmax + aggregation
// block = 1 node, 128 threads (thread t = head t>>5, channel t&31)
// single pass over incoming edges; x_l row gathered once per edge.
// ---------------------------------------------------------------------------
__global__ __launch_bounds__(128) void node_kernel(
    const float* __restrict__ xl, const float* __restrict__ xr,
    const float* __restrict__ We, const float* __restrict__ att,
    const int* __restrict__ off, const int* __restrict__ csr_src,
    const float* __restrict__ csr_ea, const float* __restrict__ bias,
    float* __restrict__ out_pre)
{
    const int n = blockIdx.x;
    const int t = threadIdx.x;
    const float xrv = xr[n * HCD + t];
    const float wev = We[t];
    const float atv = att[t];
    const int s = off[n], e = off[n + 1];

    float mx = -3.402823466e38f, sm = 0.f, acc = 0.f;
    for (int k = s; k < e; ++k) {
        const int   j   = csr_src[k];
        const float eav = csr_ea[k];
        const float xlv = xl[j * HCD + t];
        float m = xlv + xrv + eav * wev;
        m = (m > 0.f) ? m : NEG_SLOPE * m;
        float p = m * atv;
        // reduce over 32-lane head group (butterfly -> all lanes get head sum)
        p += __shfl_xor(p, 16);
        p += __shfl_xor(p, 8);
        p += __shfl_xor(p, 4);
        p += __shfl_xor(p, 2);
        p += __shfl_xor(p, 1);
        // online softmax update
        float nm = fmaxf(mx, p);
        float sc = __expf(mx - nm);   // first edge: exp(huge negative) = 0
        float ev = __expf(p - nm);
        sm  = sm * sc + ev;
        acc = acc * sc + ev * xlv;
        mx  = nm;
    }
    out_pre[n * HCD + t] = acc / (sm + 1e-16f) + bias[t];
}

// ---------------------------------------------------------------------------
// K6: BN statistics (per-channel sum & sumsq, hierarchical)
// ---------------------------------------------------------------------------
__global__ __launch_bounds__(128) void bnstat_kernel(const float* __restrict__ out_pre,
                                                     float* __restrict__ stats)
{
    const int t = threadIdx.x;
    float s = 0.f, q = 0.f;
    for (int n = blockIdx.x; n < NN; n += gridDim.x) {
        float v = out_pre[n * HCD + t];
        s += v; q += v * v;
    }
    atomicAdd(&stats[t], s);
    atomicAdd(&stats[HCD + t], q);
}

// ---------------------------------------------------------------------------
// K7: normalize + affine + ELU
// ---------------------------------------------------------------------------
__global__ __launch_bounds__(256) void bn_elu_kernel(
    const float* __restrict__ out_pre, const float* __restrict__ stats,
    const float* __restrict__ gamma, const float* __restrict__ beta,
    float* __restrict__ out)
{
    int idx = blockIdx.x * 256 + threadIdx.x;
    if (idx >= NN * HCD) return;
    int c = idx & (HCD - 1);
    float mean = stats[c] * (1.f / NN);
    float var  = stats[HCD + c] * (1.f / NN) - mean * mean;
    float inv  = rsqrtf(var + 1e-5f);
    float v = (out_pre[idx] - mean) * inv * gamma[c] + beta[c];
    out[idx] = (v > 0.f) ? v : expm1f(v);
}

// ---------------------------------------------------------------------------
extern "C" void kernel_launch(void* const* d_in, const int* in_sizes, int n_in,
                              void* d_out, int out_size, void* d_ws, size_t ws_size,
                              hipStream_t stream)
{
    (void)in_sizes; (void)n_in; (void)out_size; (void)ws_size;
    const float* x    = (const float*)d_in[0];
    const int*   ei   = (const int*)  d_in[1];   // [2,E] -> src = ei, dst = ei+NE
    const float* ea   = (const float*)d_in[2];
    const float* Wl   = (const float*)d_in[3];
    const float* bl   = (const float*)d_in[4];
    const float* Wr   = (const float*)d_in[5];
    const float* br   = (const float*)d_in[6];
    const float* We   = (const float*)d_in[7];
    const float* att  = (const float*)d_in[8];
    const float* bias = (const float*)d_in[9];
    const float* gamma= (const float*)d_in[10];
    const float* beta = (const float*)d_in[11];
    float* out = (float*)d_out;

    // workspace layout (256B-aligned regions), total ~84 MB
    char* wsb = (char*)d_ws;
    size_t o = 0;
    auto take = [&](size_t bytes) -> char* {
        char* p = wsb + o;
        o += (bytes + 255) & ~size_t(255);
        return p;
    };
    float* xl      = (float*)take(sizeof(float) * NN * HCD);
    float* xr      = (float*)take(sizeof(float) * NN * HCD);
    float* out_pre = (float*)take(sizeof(float) * NN * HCD);
    int*   csr_src = (int*)  take(sizeof(int)   * NE);
    float* csr_ea  = (float*)take(sizeof(float) * NE);
    int*   offs    = (int*)  take(sizeof(int)   * (NN + 1));
    size_t zbytes  = sizeof(int) * NN * 2 + sizeof(float) * 2 * HCD;
    char*  zbase   = take(zbytes);
    int*   deg     = (int*)zbase;
    int*   cursor  = deg + NN;
    float* stats   = (float*)(cursor + NN);

    hipMemsetAsync(zbase, 0, zbytes, stream);

    const int* srcI = ei;
    const int* dstI = ei + NE;

    gemm_xlr<<<(NN + GN - 1) / GN, 256, 0, stream>>>(x, Wl, Wr, bl, br, xl, xr);
    deg_kernel<<<(NE + 255) / 256, 256, 0, stream>>>(dstI, deg);
    scan_kernel<<<1, 1024, 0, stream>>>(deg, offs);
    fill_kernel<<<(NE + 255) / 256, 256, 0, stream>>>(srcI, dstI, ea, offs, cursor,
                                                      csr_src, csr_ea);
    node_kernel<<<NN, 128, 0, stream>>>(xl, xr, We, att, offs, csr_src, csr_ea,
                                        bias, out_pre);
    bnstat_kernel<<<256, 128, 0, stream>>>(out_pre, stats);
    bn_elu_kernel<<<(NN * HCD + 255) / 256, 256, 0, stream>>>(out_pre, stats,
                                                              gamma, beta, out);
}

// Round 2
// 321.216 us; speedup vs baseline: 1.6952x; 1.6952x over previous
//
#include <hip/hip_runtime.h>
#include <math.h>

constexpr int NN  = 50000;   // nodes
constexpr int NE  = 800000;  // edges
constexpr int IND = 128;     // input dim
constexpr int HCD = 128;     // heads*channels
constexpr float NEG_SLOPE = 0.2f;

typedef __attribute__((ext_vector_type(8))) short bf16x8;
typedef __attribute__((ext_vector_type(4))) float f32x4;

// split fp32 -> bf16 hi + bf16 lo (truncation; lo catches the residual).
// x ~= hi + lo with error ~2^-16 relative.
__device__ __forceinline__ void splitbf(float f, unsigned short &h, unsigned short &lo) {
    unsigned u = __float_as_uint(f);
    h = (unsigned short)(u >> 16);
    float fh = __uint_as_float(u & 0xffff0000u);
    lo = (unsigned short)(__float_as_uint(f - fh) >> 16);
}

// ---------------------------------------------------------------------------
// K1: MFMA split-bf16 GEMM.  grid (ceil(NN/128), 2): y=0 -> xl=x@Wl+bl,
// y=1 -> xr=x@Wr+br.  Block 256 thr = 4 waves, block tile 128x128, BK=64.
// LDS: A_hi/A_lo [row][k] bf16, B_hi/B_lo [c][k] bf16 (transposed), all
// XOR-swizzled (byte ^= (row&7)<<4) so ds_read_b128 fragments are
// conflict-free (row stride 128B would otherwise be a 16-way conflict).
// 3-term accumulation: hi*Hi + hi*Lo + lo*Hi  (fp32-accurate).
// ---------------------------------------------------------------------------
constexpr int BM = 128;
constexpr int BK = 64;

__global__ __launch_bounds__(256) void gemm_mfma(
    const float* __restrict__ x, const float* __restrict__ Wl,
    const float* __restrict__ Wr, const float* __restrict__ bl,
    const float* __restrict__ br, float* __restrict__ xl, float* __restrict__ xr)
{
    extern __shared__ char smem[];      // 64 KB
    char* Ah = smem;                    // [128][64] bf16
    char* Al = smem + 16384;
    char* Bh = smem + 32768;            // [c=128][k=64] bf16 (W transposed)
    char* Bl = smem + 49152;

    const int tid = threadIdx.x;
    const float* W  = blockIdx.y ? Wr : Wl;
    const float* bv = blockIdx.y ? br : bl;
    float* outp     = blockIdx.y ? xr : xl;
    const int bn = blockIdx.x * BM;

    const int l   = tid & 63;
    const int wid = tid >> 6;
    const int wr  = (wid >> 1) * 64;    // wave row base in tile
    const int wc  = (wid & 1) * 64;     // wave col base in tile
    const int lr  = l & 15;
    const int kg  = l >> 4;             // 0..3

    f32x4 acc[4][4];
#pragma unroll
    for (int s = 0; s < 4; ++s)
#pragma unroll
        for (int f = 0; f < 4; ++f) acc[s][f] = (f32x4){0.f, 0.f, 0.f, 0.f};

    const int cB  = tid & 127;          // B-stage column
    const int khB = tid >> 7;           // 0/1

    for (int ki = 0; ki < 2; ++ki) {
        // ---- stage A: 128 rows x 64 k (float4 coalesced loads, split, b64 writes)
#pragma unroll
        for (int r = 0; r < 8; ++r) {
            int g = tid + r * 256;           // float4 group 0..2047
            int row = g >> 4, k4 = g & 15;
            int node = bn + row;
            float4 v = make_float4(0.f, 0.f, 0.f, 0.f);
            if (node < NN) v = *(const float4*)&x[node * IND + ki * BK + k4 * 4];
            unsigned short h0, h1, h2, h3, q0, q1, q2, q3;
            splitbf(v.x, h0, q0); splitbf(v.y, h1, q1);
            splitbf(v.z, h2, q2); splitbf(v.w, h3, q3);
            int off = (row * BK + k4 * 4) * 2;
            int swz = off ^ ((row & 7) << 4);
            *(ushort4*)(Ah + swz) = make_ushort4(h0, h1, h2, h3);
            *(ushort4*)(Al + swz) = make_ushort4(q0, q1, q2, q3);
        }
        // ---- stage B transposed: [c][k], coalesced-over-c global reads
#pragma unroll
        for (int r = 0; r < 8; ++r) {
            int kb = r * 8 + khB * 4;        // 4 consecutive k
            float f0 = W[(ki * BK + kb + 0) * HCD + cB];
            float f1 = W[(ki * BK + kb + 1) * HCD + cB];
            float f2 = W[(ki * BK + kb + 2) * HCD + cB];
            float f3 = W[(ki * BK + kb + 3) * HCD + cB];
            unsigned short h0, h1, h2, h3, q0, q1, q2, q3;
            splitbf(f0, h0, q0); splitbf(f1, h1, q1);
            splitbf(f2, h2, q2); splitbf(f3, h3, q3);
            int off = (cB * BK + kb) * 2;
            int swz = off ^ ((cB & 7) << 4);
            *(ushort4*)(Bh + swz) = make_ushort4(h0, h1, h2, h3);
            *(ushort4*)(Bl + swz) = make_ushort4(q0, q1, q2, q3);
        }
        __syncthreads();
#pragma unroll
        for (int kk = 0; kk < 2; ++kk) {
            bf16x8 Bfh[4], Bfl[4];
#pragma unroll
            for (int f = 0; f < 4; ++f) {
                int c = wc + f * 16 + lr;
                int swz = (c * 128 + kk * 64 + kg * 16) ^ ((c & 7) << 4);
                Bfh[f] = *(const bf16x8*)(Bh + swz);
                Bfl[f] = *(const bf16x8*)(Bl + swz);
            }
#pragma unroll
            for (int s = 0; s < 4; ++s) {
                int row = wr + s * 16 + lr;
                int swz = (row * 128 + kk * 64 + kg * 16) ^ ((row & 7) << 4);
                bf16x8 Afh = *(const bf16x8*)(Ah + swz);
                bf16x8 Afl = *(const bf16x8*)(Al + swz);
#pragma unroll
                for (int f = 0; f < 4; ++f) {
                    acc[s][f] = __builtin_amdgcn_mfma_f32_16x16x32_bf16(Afh, Bfh[f], acc[s][f], 0, 0, 0);
                    acc[s][f] = __builtin_amdgcn_mfma_f32_16x16x32_bf16(Afh, Bfl[f], acc[s][f], 0, 0, 0);
                    acc[s][f] = __builtin_amdgcn_mfma_f32_16x16x32_bf16(Afl, Bfh[f], acc[s][f], 0, 0, 0);
                }
            }
        }
        __syncthreads();
    }
    // epilogue: C/D layout col = lane&15, row = (lane>>4)*4 + j
#pragma unroll
    for (int s = 0; s < 4; ++s)
#pragma unroll
        for (int f = 0; f < 4; ++f) {
            int c = wc + f * 16 + lr;
            float bb = bv[c];
#pragma unroll
            for (int j = 0; j < 4; ++j) {
                int r = bn + wr + s * 16 + kg * 4 + j;
                if (r < NN) outp[r * HCD + c] = acc[s][f][j] + bb;
            }
        }
}

// ---------------------------------------------------------------------------
// K2: in-degree count
// ---------------------------------------------------------------------------
__global__ __launch_bounds__(256) void deg_kernel(const int* __restrict__ dst,
                                                  int* __restrict__ deg)
{
    int e = blockIdx.x * 256 + threadIdx.x;
    if (e < NE) atomicAdd(&deg[dst[e]], 1);
}

// ---------------------------------------------------------------------------
// K3a/b/c: 3-phase coalesced exclusive scan of deg -> off
// ---------------------------------------------------------------------------
constexpr int SB = (NN + 255) / 256;   // 196 scan blocks

__global__ __launch_bounds__(256) void scan1(const int* __restrict__ deg,
                                             int* __restrict__ bsum)
{
    __shared__ int red[4];
    int idx = blockIdx.x * 256 + threadIdx.x;
    int v = (idx < NN) ? deg[idx] : 0;
    for (int d = 32; d; d >>= 1) v += __shfl_down(v, d);
    if ((threadIdx.x & 63) == 0) red[threadIdx.x >> 6] = v;
    __syncthreads();
    if (threadIdx.x == 0) bsum[blockIdx.x] = red[0] + red[1] + red[2] + red[3];
}

__global__ __launch_bounds__(256) void scan2(const int* __restrict__ bsum,
                                             int* __restrict__ boff)
{
    __shared__ int t[256];
    int tid = threadIdx.x;
    int v = (tid < SB) ? bsum[tid] : 0;
    t[tid] = v;
    __syncthreads();
    for (int d = 1; d < 256; d <<= 1) {
        int u = (tid >= d) ? t[tid - d] : 0;
        __syncthreads();
        t[tid] += u;
        __syncthreads();
    }
    boff[tid] = t[tid] - v;   // exclusive
}

__global__ __launch_bounds__(256) void scan3(const int* __restrict__ deg,
                                             const int* __restrict__ boff,
                                             int* __restrict__ off)
{
    __shared__ int t[256];
    int tid = threadIdx.x;
    int idx = blockIdx.x * 256 + tid;
    int v = (idx < NN) ? deg[idx] : 0;
    t[tid] = v;
    __syncthreads();
    for (int d = 1; d < 256; d <<= 1) {
        int u = (tid >= d) ? t[tid - d] : 0;
        __syncthreads();
        t[tid] += u;
        __syncthreads();
    }
    int excl = t[tid] - v + boff[blockIdx.x];
    if (idx < NN) off[idx] = excl;
    if (idx == NN - 1) off[NN] = excl + v;
}

// ---------------------------------------------------------------------------
// K4: CSR fill
// ---------------------------------------------------------------------------
__global__ __launch_bounds__(256) void fill_kernel(
    const int* __restrict__ src, const int* __restrict__ dst,
    const float* __restrict__ ea, const int* __restrict__ off,
    int* __restrict__ cursor, int* __restrict__ csr_src, float* __restrict__ csr_ea)
{
    int e = blockIdx.x * 256 + threadIdx.x;
    if (e >= NE) return;
    int d = dst[e];
    int pos = atomicAdd(&cursor[d], 1);
    int idx = off[d] + pos;
    csr_src[idx] = src[e];
    csr_ea[idx]  = ea[e];
}

// ---------------------------------------------------------------------------
// K5: per-node fused attention + online softmax + aggregation.
// One wave per node (4 nodes / 256-thr block); lane l owns channels 2l,2l+1
// (head = l>>4); gather is one contiguous 512B float2 read per edge per wave.
// ---------------------------------------------------------------------------
__global__ __launch_bounds__(256) void node_kernel(
    const float* __restrict__ xl, const float* __restrict__ xr,
    const float* __restrict__ We, const float* __restrict__ att,
    const int* __restrict__ off, const int* __restrict__ csr_src,
    const float* __restrict__ csr_ea, const float* __restrict__ bias,
    float* __restrict__ out_pre)
{
    int n = blockIdx.x * 4 + (threadIdx.x >> 6);
    if (n >= NN) return;
    int l  = threadIdx.x & 63;
    int c0 = l * 2;
    float2 xrv = *(const float2*)&xr[n * HCD + c0];
    float2 wev = *(const float2*)&We[c0];
    float2 atv = *(const float2*)&att[c0];
    int s = off[n], e = off[n + 1];

    float mx = -3.402823466e38f, sm = 0.f, a0 = 0.f, a1 = 0.f;
    for (int k = s; k < e; ++k) {
        int   j   = csr_src[k];
        float eav = csr_ea[k];
        float2 xlv = *(const float2*)&xl[j * HCD + c0];
        float m0 = xlv.x + xrv.x + eav * wev.x;
        float m1 = xlv.y + xrv.y + eav * wev.y;
        m0 = (m0 > 0.f) ? m0 : NEG_SLOPE * m0;
        m1 = (m1 > 0.f) ? m1 : NEG_SLOPE * m1;
        float p = m0 * atv.x + m1 * atv.y;
        p += __shfl_xor(p, 8);
        p += __shfl_xor(p, 4);
        p += __shfl_xor(p, 2);
        p += __shfl_xor(p, 1);
        float nm = fmaxf(mx, p);
        float sc = __expf(mx - nm);
        float ev = __expf(p - nm);
        sm = sm * sc + ev;
        a0 = a0 * sc + ev * xlv.x;
        a1 = a1 * sc + ev * xlv.y;
        mx = nm;
    }
    float inv = 1.f / (sm + 1e-16f);
    float2 o;
    o.x = a0 * inv + bias[c0];
    o.y = a1 * inv + bias[c0 + 1];
    *(float2*)&out_pre[n * HCD + c0] = o;
}

// ---------------------------------------------------------------------------
// K6: BN statistics (per-channel sum & sumsq)
// ---------------------------------------------------------------------------
__global__ __launch_bounds__(128) void bnstat_kernel(const float* __restrict__ out_pre,
                                                     float* __restrict__ stats)
{
    const int t = threadIdx.x;
    float s = 0.f, q = 0.f;
    for (int n = blockIdx.x; n < NN; n += gridDim.x) {
        float v = out_pre[n * HCD + t];
        s += v; q += v * v;
    }
    atomicAdd(&stats[t], s);
    atomicAdd(&stats[HCD + t], q);
}

// ---------------------------------------------------------------------------
// K7: normalize + affine + ELU  (float4)
// ---------------------------------------------------------------------------
__global__ __launch_bounds__(256) void bn_elu_kernel(
    const float* __restrict__ out_pre, const float* __restrict__ stats,
    const float* __restrict__ gamma, const float* __restrict__ beta,
    float* __restrict__ out)
{
    int i4 = blockIdx.x * 256 + threadIdx.x;
    if (i4 >= NN * HCD / 4) return;
    int c4 = (i4 & 31) * 4;
    float4 v = *(const float4*)&out_pre[i4 * 4];
    float o[4] = {v.x, v.y, v.z, v.w};
#pragma unroll
    for (int j = 0; j < 4; ++j) {
        int c = c4 + j;
        float mean = stats[c] * (1.f / NN);
        float var  = stats[HCD + c] * (1.f / NN) - mean * mean;
        float inv  = rsqrtf(var + 1e-5f);
        float t = (o[j] - mean) * inv * gamma[c] + beta[c];
        o[j] = (t > 0.f) ? t : expm1f(t);
    }
    *(float4*)&((float*)out)[i4 * 4] = make_float4(o[0], o[1], o[2], o[3]);
}

// ---------------------------------------------------------------------------
extern "C" void kernel_launch(void* const* d_in, const int* in_sizes, int n_in,
                              void* d_out, int out_size, void* d_ws, size_t ws_size,
                              hipStream_t stream)
{
    (void)in_sizes; (void)n_in; (void)out_size; (void)ws_size;
    const float* x    = (const float*)d_in[0];
    const int*   ei   = (const int*)  d_in[1];
    const float* ea   = (const float*)d_in[2];
    const float* Wl   = (const float*)d_in[3];
    const float* bl   = (const float*)d_in[4];
    const float* Wr   = (const float*)d_in[5];
    const float* br   = (const float*)d_in[6];
    const float* We   = (const float*)d_in[7];
    const float* att  = (const float*)d_in[8];
    const float* bias = (const float*)d_in[9];
    const float* gamma= (const float*)d_in[10];
    const float* beta = (const float*)d_in[11];
    float* out = (float*)d_out;

    char* wsb = (char*)d_ws;
    size_t o = 0;
    auto take = [&](size_t bytes) -> char* {
        char* p = wsb + o;
        o += (bytes + 255) & ~size_t(255);
        return p;
    };
    float* xl      = (float*)take(sizeof(float) * NN * HCD);
    float* xr      = (float*)take(sizeof(float) * NN * HCD);
    float* out_pre = (float*)take(sizeof(float) * NN * HCD);
    int*   csr_src = (int*)  take(sizeof(int)   * NE);
    float* csr_ea  = (float*)take(sizeof(float) * NE);
    int*   offs    = (int*)  take(sizeof(int)   * (NN + 1));
    int*   bsum    = (int*)  take(sizeof(int)   * 256);
    int*   boff    = (int*)  take(sizeof(int)   * 256);
    size_t zbytes  = sizeof(int) * NN * 2 + sizeof(float) * 2 * HCD;
    char*  zbase   = take(zbytes);
    int*   deg     = (int*)zbase;
    int*   cursor  = deg + NN;
    float* stats   = (float*)(cursor + NN);

    hipMemsetAsync(zbase, 0, zbytes, stream);

    const int* srcI = ei;
    const int* dstI = ei + NE;

    gemm_mfma<<<dim3((NN + BM - 1) / BM, 2), 256, 65536, stream>>>(
        x, Wl, Wr, bl, br, xl, xr);
    deg_kernel<<<(NE + 255) / 256, 256, 0, stream>>>(dstI, deg);
    scan1<<<SB, 256, 0, stream>>>(deg, bsum);
    scan2<<<1, 256, 0, stream>>>(bsum, boff);
    scan3<<<SB, 256, 0, stream>>>(deg, boff, offs);
    fill_kernel<<<(NE + 255) / 256, 256, 0, stream>>>(srcI, dstI, ea, offs, cursor,
                                                      csr_src, csr_ea);
    node_kernel<<<(NN + 3) / 4, 256, 0, stream>>>(xl, xr, We, att, offs, csr_src,
                                                  csr_ea, bias, out_pre);
    bnstat_kernel<<<512, 128, 0, stream>>>(out_pre, stats);
    bn_elu_kernel<<<(NN * HCD / 4 + 255) / 256, 256, 0, stream>>>(out_pre, stats,
                                                                  gamma, beta, out);
}

// Round 3
// 300.178 us; speedup vs baseline: 1.8140x; 1.0701x over previous
//
#include <hip/hip_runtime.h>
#include <math.h>

constexpr int NN  = 50000;   // nodes
constexpr int NE  = 800000;  // edges
constexpr int IND = 128;     // input dim
constexpr int HCD = 128;     // heads*channels
constexpr float NEG_SLOPE = 0.2f;

typedef __attribute__((ext_vector_type(8))) short bf16x8;
typedef __attribute__((ext_vector_type(4))) float f32x4;

// split fp32 -> bf16 hi + bf16 lo (truncation; lo catches the residual).
__device__ __forceinline__ void splitbf(float f, unsigned short &h, unsigned short &lo) {
    unsigned u = __float_as_uint(f);
    h = (unsigned short)(u >> 16);
    float fh = __uint_as_float(u & 0xffff0000u);
    lo = (unsigned short)(__float_as_uint(f - fh) >> 16);
}

// ---------------------------------------------------------------------------
// K1: MFMA split-bf16 GEMM (grid.y: 0 -> xl = x@Wl+bl, 1 -> xr = x@Wr+br)
// ---------------------------------------------------------------------------
constexpr int BM = 128;
constexpr int BK = 64;

__global__ __launch_bounds__(256) void gemm_mfma(
    const float* __restrict__ x, const float* __restrict__ Wl,
    const float* __restrict__ Wr, const float* __restrict__ bl,
    const float* __restrict__ br, float* __restrict__ xl, float* __restrict__ xr)
{
    extern __shared__ char smem[];      // 64 KB
    char* Ah = smem;                    // [128][64] bf16
    char* Al = smem + 16384;
    char* Bh = smem + 32768;            // [c=128][k=64] bf16 (W transposed)
    char* Bl = smem + 49152;

    const int tid = threadIdx.x;
    const float* W  = blockIdx.y ? Wr : Wl;
    const float* bv = blockIdx.y ? br : bl;
    float* outp     = blockIdx.y ? xr : xl;
    const int bn = blockIdx.x * BM;

    const int l   = tid & 63;
    const int wid = tid >> 6;
    const int wr  = (wid >> 1) * 64;
    const int wc  = (wid & 1) * 64;
    const int lr  = l & 15;
    const int kg  = l >> 4;

    f32x4 acc[4][4];
#pragma unroll
    for (int s = 0; s < 4; ++s)
#pragma unroll
        for (int f = 0; f < 4; ++f) acc[s][f] = (f32x4){0.f, 0.f, 0.f, 0.f};

    const int cB  = tid & 127;
    const int khB = tid >> 7;

    for (int ki = 0; ki < 2; ++ki) {
#pragma unroll
        for (int r = 0; r < 8; ++r) {
            int g = tid + r * 256;
            int row = g >> 4, k4 = g & 15;
            int node = bn + row;
            float4 v = make_float4(0.f, 0.f, 0.f, 0.f);
            if (node < NN) v = *(const float4*)&x[node * IND + ki * BK + k4 * 4];
            unsigned short h0, h1, h2, h3, q0, q1, q2, q3;
            splitbf(v.x, h0, q0); splitbf(v.y, h1, q1);
            splitbf(v.z, h2, q2); splitbf(v.w, h3, q3);
            int off = (row * BK + k4 * 4) * 2;
            int swz = off ^ ((row & 7) << 4);
            *(ushort4*)(Ah + swz) = make_ushort4(h0, h1, h2, h3);
            *(ushort4*)(Al + swz) = make_ushort4(q0, q1, q2, q3);
        }
#pragma unroll
        for (int r = 0; r < 8; ++r) {
            int kb = r * 8 + khB * 4;
            float f0 = W[(ki * BK + kb + 0) * HCD + cB];
            float f1 = W[(ki * BK + kb + 1) * HCD + cB];
            float f2 = W[(ki * BK + kb + 2) * HCD + cB];
            float f3 = W[(ki * BK + kb + 3) * HCD + cB];
            unsigned short h0, h1, h2, h3, q0, q1, q2, q3;
            splitbf(f0, h0, q0); splitbf(f1, h1, q1);
            splitbf(f2, h2, q2); splitbf(f3, h3, q3);
            int off = (cB * BK + kb) * 2;
            int swz = off ^ ((cB & 7) << 4);
            *(ushort4*)(Bh + swz) = make_ushort4(h0, h1, h2, h3);
            *(ushort4*)(Bl + swz) = make_ushort4(q0, q1, q2, q3);
        }
        __syncthreads();
#pragma unroll
        for (int kk = 0; kk < 2; ++kk) {
            bf16x8 Bfh[4], Bfl[4];
#pragma unroll
            for (int f = 0; f < 4; ++f) {
                int c = wc + f * 16 + lr;
                int swz = (c * 128 + kk * 64 + kg * 16) ^ ((c & 7) << 4);
                Bfh[f] = *(const bf16x8*)(Bh + swz);
                Bfl[f] = *(const bf16x8*)(Bl + swz);
            }
#pragma unroll
            for (int s = 0; s < 4; ++s) {
                int row = wr + s * 16 + lr;
                int swz = (row * 128 + kk * 64 + kg * 16) ^ ((row & 7) << 4);
                bf16x8 Afh = *(const bf16x8*)(Ah + swz);
                bf16x8 Afl = *(const bf16x8*)(Al + swz);
#pragma unroll
                for (int f = 0; f < 4; ++f) {
                    acc[s][f] = __builtin_amdgcn_mfma_f32_16x16x32_bf16(Afh, Bfh[f], acc[s][f], 0, 0, 0);
                    acc[s][f] = __builtin_amdgcn_mfma_f32_16x16x32_bf16(Afh, Bfl[f], acc[s][f], 0, 0, 0);
                    acc[s][f] = __builtin_amdgcn_mfma_f32_16x16x32_bf16(Afl, Bfh[f], acc[s][f], 0, 0, 0);
                }
            }
        }
        __syncthreads();
    }
#pragma unroll
    for (int s = 0; s < 4; ++s)
#pragma unroll
        for (int f = 0; f < 4; ++f) {
            int c = wc + f * 16 + lr;
            float bb = bv[c];
#pragma unroll
            for (int j = 0; j < 4; ++j) {
                int r = bn + wr + s * 16 + kg * 4 + j;
                if (r < NN) outp[r * HCD + c] = acc[s][f][j] + bb;
            }
        }
}

// ---------------------------------------------------------------------------
// K2: in-degree count
// ---------------------------------------------------------------------------
__global__ __launch_bounds__(256) void deg_kernel(const int* __restrict__ dst,
                                                  int* __restrict__ deg)
{
    int e = blockIdx.x * 256 + threadIdx.x;
    if (e < NE) atomicAdd(&deg[dst[e]], 1);
}

// ---------------------------------------------------------------------------
// K3a/b/c: 3-phase coalesced exclusive scan of deg -> off
// ---------------------------------------------------------------------------
constexpr int SB = (NN + 255) / 256;   // 196 scan blocks

__global__ __launch_bounds__(256) void scan1(const int* __restrict__ deg,
                                             int* __restrict__ bsum)
{
    __shared__ int red[4];
    int idx = blockIdx.x * 256 + threadIdx.x;
    int v = (idx < NN) ? deg[idx] : 0;
    for (int d = 32; d; d >>= 1) v += __shfl_down(v, d);
    if ((threadIdx.x & 63) == 0) red[threadIdx.x >> 6] = v;
    __syncthreads();
    if (threadIdx.x == 0) bsum[blockIdx.x] = red[0] + red[1] + red[2] + red[3];
}

__global__ __launch_bounds__(256) void scan2(const int* __restrict__ bsum,
                                             int* __restrict__ boff)
{
    __shared__ int t[256];
    int tid = threadIdx.x;
    int v = (tid < SB) ? bsum[tid] : 0;
    t[tid] = v;
    __syncthreads();
    for (int d = 1; d < 256; d <<= 1) {
        int u = (tid >= d) ? t[tid - d] : 0;
        __syncthreads();
        t[tid] += u;
        __syncthreads();
    }
    boff[tid] = t[tid] - v;
}

__global__ __launch_bounds__(256) void scan3(const int* __restrict__ deg,
                                             const int* __restrict__ boff,
                                             int* __restrict__ off)
{
    __shared__ int t[256];
    int tid = threadIdx.x;
    int idx = blockIdx.x * 256 + tid;
    int v = (idx < NN) ? deg[idx] : 0;
    t[tid] = v;
    __syncthreads();
    for (int d = 1; d < 256; d <<= 1) {
        int u = (tid >= d) ? t[tid - d] : 0;
        __syncthreads();
        t[tid] += u;
        __syncthreads();
    }
    int excl = t[tid] - v + boff[blockIdx.x];
    if (idx < NN) off[idx] = excl;
    if (idx == NN - 1) off[NN] = excl + v;
}

// ---------------------------------------------------------------------------
// K4: CSR fill — packed (src, ea) int2, single 8B store per edge
// ---------------------------------------------------------------------------
__global__ __launch_bounds__(256) void fill_kernel(
    const int* __restrict__ src, const int* __restrict__ dst,
    const float* __restrict__ ea, const int* __restrict__ off,
    int* __restrict__ cursor, int2* __restrict__ csr)
{
    int e = blockIdx.x * 256 + threadIdx.x;
    if (e >= NE) return;
    int d = dst[e];
    int pos = atomicAdd(&cursor[d], 1);
    csr[off[d] + pos] = make_int2(src[e], __float_as_int(ea[e]));
}

// ---------------------------------------------------------------------------
// K5: per-node attention + defer-max online softmax + aggregation.
// One wave per node; lane l owns channels 2l,2l+1 (head = l>>4).
// 2-edge unroll, 1-pair-deep prefetch; rescale only when p > mx+8.
// ---------------------------------------------------------------------------
__global__ __launch_bounds__(256) void node_kernel(
    const float* __restrict__ xl, const float* __restrict__ xr,
    const float* __restrict__ We, const float* __restrict__ att,
    const int* __restrict__ off, const int2* __restrict__ csr,
    const float* __restrict__ bias, float* __restrict__ out_pre)
{
    int n = blockIdx.x * 4 + (threadIdx.x >> 6);
    if (n >= NN) return;
    int l  = threadIdx.x & 63;
    int c0 = l * 2;
    float2 xrv = *(const float2*)&xr[n * HCD + c0];
    float2 wev = *(const float2*)&We[c0];
    float2 atv = *(const float2*)&att[c0];
    const int s = off[n], e = off[n + 1];

    float mx = -3.402823466e38f, sm = 0.f, a0 = 0.f, a1 = 0.f;

    // score of one edge (independent chain; ends in 4-step shfl reduce)
    auto score = [&](float2 xlv, float eav) -> float {
        float m0 = xlv.x + xrv.x + eav * wev.x;
        float m1 = xlv.y + xrv.y + eav * wev.y;
        m0 = (m0 > 0.f) ? m0 : NEG_SLOPE * m0;
        m1 = (m1 > 0.f) ? m1 : NEG_SLOPE * m1;
        float p = m0 * atv.x + m1 * atv.y;
        p += __shfl_xor(p, 8);
        p += __shfl_xor(p, 4);
        p += __shfl_xor(p, 2);
        p += __shfl_xor(p, 1);
        return p;
    };

    int k = s;
    int2 cA, cB; float2 xA, xB;
    if (k < e)     { cA = csr[k];     xA = *(const float2*)&xl[cA.x * HCD + c0]; }
    if (k + 1 < e) { cB = csr[k + 1]; xB = *(const float2*)&xl[cB.x * HCD + c0]; }

    for (; k + 2 <= e; k += 2) {
        int2 cC, cD; float2 xC, xD;
        if (k + 2 < e) { cC = csr[k + 2]; xC = *(const float2*)&xl[cC.x * HCD + c0]; }
        if (k + 3 < e) { cD = csr[k + 3]; xD = *(const float2*)&xl[cD.x * HCD + c0]; }

        float pA = score(xA, __int_as_float(cA.y));
        float pB = score(xB, __int_as_float(cB.y));
        float pm = fmaxf(pA, pB);
        if (pm > mx + 8.f) {                      // rare rescale
            float sc = __expf(mx - pm);
            sm *= sc; a0 *= sc; a1 *= sc; mx = pm;
        }
        float evA = __expf(pA - mx);
        float evB = __expf(pB - mx);
        sm += evA + evB;
        a0 = fmaf(evA, xA.x, fmaf(evB, xB.x, a0));
        a1 = fmaf(evA, xA.y, fmaf(evB, xB.y, a1));

        cA = cC; xA = xC; cB = cD; xB = xD;
    }
    if (k < e) {                                   // odd tail (edge in A regs)
        float pA = score(xA, __int_as_float(cA.y));
        if (pA > mx + 8.f) {
            float sc = __expf(mx - pA);
            sm *= sc; a0 *= sc; a1 *= sc; mx = pA;
        }
        float evA = __expf(pA - mx);
        sm += evA;
        a0 = fmaf(evA, xA.x, a0);
        a1 = fmaf(evA, xA.y, a1);
    }

    float inv = 1.f / (sm + 1e-16f);
    float2 o;
    o.x = a0 * inv + bias[c0];
    o.y = a1 * inv + bias[c0 + 1];
    *(float2*)&out_pre[n * HCD + c0] = o;
}

// ---------------------------------------------------------------------------
// K6: BN statistics (per-channel sum & sumsq)
// ---------------------------------------------------------------------------
__global__ __launch_bounds__(128) void bnstat_kernel(const float* __restrict__ out_pre,
                                                     float* __restrict__ stats)
{
    const int t = threadIdx.x;
    float s = 0.f, q = 0.f;
    for (int n = blockIdx.x; n < NN; n += gridDim.x) {
        float v = out_pre[n * HCD + t];
        s += v; q += v * v;
    }
    atomicAdd(&stats[t], s);
    atomicAdd(&stats[HCD + t], q);
}

// ---------------------------------------------------------------------------
// K7: normalize + affine + ELU  (float4)
// ---------------------------------------------------------------------------
__global__ __launch_bounds__(256) void bn_elu_kernel(
    const float* __restrict__ out_pre, const float* __restrict__ stats,
    const float* __restrict__ gamma, const float* __restrict__ beta,
    float* __restrict__ out)
{
    int i4 = blockIdx.x * 256 + threadIdx.x;
    if (i4 >= NN * HCD / 4) return;
    int c4 = (i4 & 31) * 4;
    float4 v = *(const float4*)&out_pre[i4 * 4];
    float o[4] = {v.x, v.y, v.z, v.w};
#pragma unroll
    for (int j = 0; j < 4; ++j) {
        int c = c4 + j;
        float mean = stats[c] * (1.f / NN);
        float var  = stats[HCD + c] * (1.f / NN) - mean * mean;
        float inv  = rsqrtf(var + 1e-5f);
        float t = (o[j] - mean) * inv * gamma[c] + beta[c];
        o[j] = (t > 0.f) ? t : expm1f(t);
    }
    *(float4*)&((float*)out)[i4 * 4] = make_float4(o[0], o[1], o[2], o[3]);
}

// ---------------------------------------------------------------------------
extern "C" void kernel_launch(void* const* d_in, const int* in_sizes, int n_in,
                              void* d_out, int out_size, void* d_ws, size_t ws_size,
                              hipStream_t stream)
{
    (void)in_sizes; (void)n_in; (void)out_size; (void)ws_size;
    const float* x    = (const float*)d_in[0];
    const int*   ei   = (const int*)  d_in[1];
    const float* ea   = (const float*)d_in[2];
    const float* Wl   = (const float*)d_in[3];
    const float* bl   = (const float*)d_in[4];
    const float* Wr   = (const float*)d_in[5];
    const float* br   = (const float*)d_in[6];
    const float* We   = (const float*)d_in[7];
    const float* att  = (const float*)d_in[8];
    const float* bias = (const float*)d_in[9];
    const float* gamma= (const float*)d_in[10];
    const float* beta = (const float*)d_in[11];
    float* out = (float*)d_out;

    char* wsb = (char*)d_ws;
    size_t o = 0;
    auto take = [&](size_t bytes) -> char* {
        char* p = wsb + o;
        o += (bytes + 255) & ~size_t(255);
        return p;
    };
    float* xl      = (float*)take(sizeof(float) * NN * HCD);
    float* xr      = (float*)take(sizeof(float) * NN * HCD);
    float* out_pre = (float*)take(sizeof(float) * NN * HCD);
    int2*  csr     = (int2*) take(sizeof(int2)  * NE);
    int*   offs    = (int*)  take(sizeof(int)   * (NN + 1));
    int*   bsum    = (int*)  take(sizeof(int)   * 256);
    int*   boff    = (int*)  take(sizeof(int)   * 256);
    size_t zbytes  = sizeof(int) * NN * 2 + sizeof(float) * 2 * HCD;
    char*  zbase   = take(zbytes);
    int*   deg     = (int*)zbase;
    int*   cursor  = deg + NN;
    float* stats   = (float*)(cursor + NN);

    hipMemsetAsync(zbase, 0, zbytes, stream);

    const int* srcI = ei;
    const int* dstI = ei + NE;

    gemm_mfma<<<dim3((NN + BM - 1) / BM, 2), 256, 65536, stream>>>(
        x, Wl, Wr, bl, br, xl, xr);
    deg_kernel<<<(NE + 255) / 256, 256, 0, stream>>>(dstI, deg);
    scan1<<<SB, 256, 0, stream>>>(deg, bsum);
    scan2<<<1, 256, 0, stream>>>(bsum, boff);
    scan3<<<SB, 256, 0, stream>>>(deg, boff, offs);
    fill_kernel<<<(NE + 255) / 256, 256, 0, stream>>>(srcI, dstI, ea, offs, cursor, csr);
    node_kernel<<<(NN + 3) / 4, 256, 0, stream>>>(xl, xr, We, att, offs, csr,
                                                  bias, out_pre);
    bnstat_kernel<<<512, 128, 0, stream>>>(out_pre, stats);
    bn_elu_kernel<<<(NN * HCD / 4 + 255) / 256, 256, 0, stream>>>(out_pre, stats,
                                                                  gamma, beta, out);
}